// Round 4
// baseline (774.448 us; speedup 1.0000x reference)
//
#include <hip/hip_runtime.h>
#include <math.h>

// VanillaRNN: B=1024, T=512, I=64, H=128, O=10, fp32.
// One block per batch element. 512 threads = 8 waves.
// Output j = wave*16 + (lane&15); K-slice q = lane>>4 (4 slices x 48).
// All 4 slices of j live in ONE wave -> combine with shfl_xor(16)+shfl_xor(32).
// CRITICAL (rounds 1-3): the compiler remats/sinks loop-invariant weight
// loads into the loop (VGPR_Count 40-84, never resident) -> an empty
// `asm volatile("" : "+v")` pin after preload makes each w[m] opaque and
// forces true residency. Operand vector [h | x_t] in ping-pong LDS -> ONE
// barrier per step; LDS reads are 4-distinct-address broadcasts (free-ish).

#define T_STEPS 512
#define I_DIM   64
#define H_DIM   128
#define O_DIM   10
#define KTOT    192   // H + I
#define WPT     48    // K-slice per thread
#define NTHR    512

__global__ __launch_bounds__(NTHR)
__attribute__((amdgpu_waves_per_eu(1, 4)))
void rnn_fused_kernel(
    const float* __restrict__ x,      // [B, T, I]
    const float* __restrict__ W_hx,   // [H, I]
    const float* __restrict__ W_hh,   // [H, H]
    const float* __restrict__ b_hh,   // [H]
    const float* __restrict__ W_ph,   // [O, H]
    const float* __restrict__ b_ph,   // [O]
    float* __restrict__ out)          // [B, O]
{
    const int b    = blockIdx.x;
    const int tid  = threadIdx.x;
    const int wave = tid >> 6;                    // 0..7
    const int lane = tid & 63;
    const int q    = lane >> 4;                   // K-slice 0..3
    const int j    = (wave << 4) | (lane & 15);   // output row 0..127

    __shared__ float v[2][KTOT];                  // ping-pong: [0:128)=h, [128:192)=x_t

    // --- Preload this thread's 48-float slice of row j of [W_hh | W_hx] ---
    float w[WPT];
    #pragma unroll
    for (int m = 0; m < WPT; ++m) {
        const int k = q * WPT + m;
        w[m] = (k < H_DIM) ? W_hh[j * H_DIM + k]
                           : W_hx[j * I_DIM + (k - H_DIM)];
    }
    // Pin every weight into a VGPR: opaque to the compiler, so the loads
    // above CANNOT be sunk/rematerialized inside the time loop.
    #pragma unroll
    for (int m = 0; m < WPT; ++m) {
        asm volatile("" : "+v"(w[m]));
    }
    const float bias = b_hh[j];

    const float* xb = x + (size_t)b * T_STEPS * I_DIM;

    // h0 = 0; stage x_0 into buffer 0.
    if (tid < H_DIM) v[0][tid] = 0.0f;
    if (tid < I_DIM) v[0][H_DIM + tid] = xb[tid];
    __syncthreads();

    for (int t = 0; t < T_STEPS; ++t) {
        const int p = t & 1;

        // Prefetch x_{t+1} (overlaps the dot-product below).
        float xreg = 0.0f;
        const int tn = (t < T_STEPS - 1) ? (t + 1) : (T_STEPS - 1);
        if (tid < I_DIM) xreg = xb[tn * I_DIM + tid];

        // 48-MAC partial dot; operands via LDS broadcast (4 distinct addrs).
        const float4* vp4 = (const float4*)&v[p][q * WPT];
        float a0 = 0.f, a1 = 0.f, a2 = 0.f, a3 = 0.f;
        #pragma unroll
        for (int m = 0; m < WPT / 4; ++m) {
            const float4 o = vp4[m];
            a0 = fmaf(w[4*m+0], o.x, a0);
            a1 = fmaf(w[4*m+1], o.y, a1);
            a2 = fmaf(w[4*m+2], o.z, a2);
            a3 = fmaf(w[4*m+3], o.w, a3);
        }
        float acc = (a0 + a1) + (a2 + a3);

        // Combine the 4 K-slices (lane bits 4 and 5 index q).
        acc += __shfl_xor(acc, 16);
        acc += __shfl_xor(acc, 32);
        const float s = acc + bias;

        // tanh(s) = 1 - 2/(e^{2s}+1) via exp2 + rcp; saturates correctly.
        const float e = __builtin_amdgcn_exp2f(s * 2.885390081777926825f); // 2*log2(e)
        const float r = __builtin_amdgcn_rcpf(e + 1.0f);
        const float hnew = fmaf(-2.0f, r, 1.0f);

        // Write next-step state into the other buffer (no WAR on v[p]).
        if (q == 0) v[1 - p][j] = hnew;                 // lanes 0..15 per wave
        if (tid < I_DIM) v[1 - p][H_DIM + tid] = xreg;
        __syncthreads();                                 // one barrier per step
    }

    // After t=511 (p=1), final h sits in v[0][0:128).
    if (tid < O_DIM) {
        float acc = b_ph[tid];
        #pragma unroll 4
        for (int k = 0; k < H_DIM; ++k) acc = fmaf(W_ph[tid * H_DIM + k], v[0][k], acc);
        out[b * O_DIM + tid] = acc;
    }
}

extern "C" void kernel_launch(void* const* d_in, const int* in_sizes, int n_in,
                              void* d_out, int out_size, void* d_ws, size_t ws_size,
                              hipStream_t stream) {
    const float* x    = (const float*)d_in[0];
    const float* W_hx = (const float*)d_in[1];
    const float* W_hh = (const float*)d_in[2];
    const float* b_hh = (const float*)d_in[3];
    const float* W_ph = (const float*)d_in[4];
    const float* b_ph = (const float*)d_in[5];
    float* out = (float*)d_out;

    const int B = 1024;
    rnn_fused_kernel<<<B, NTHR, 0, stream>>>(x, W_hx, W_hh, b_hh, W_ph, b_ph, out);
}

// Round 5
// 554.964 us; speedup vs baseline: 1.3955x; 1.3955x over previous
//
#include <hip/hip_runtime.h>
#include <math.h>

// VanillaRNN via MFMA: B=1024, T=512, I=64, H=128, O=10, fp32 in/out.
// Block = 16 batch rows (64 blocks), 256 threads = 4 waves.
// Per step: S[16x128] = V[16x192] @ W_cat^T via mfma_f32_16x16x32_bf16.
//   wave w owns N columns [32w, 32w+32) as two 16x16 N-tiles.
//   K = 192: 4 k-tiles from h (LDS, bf16), 2 k-tiles from x (global, prefetched).
// Weights preloaded once as B-fragments in VGPRs (48 regs), asm-pinned so the
// compiler cannot remat the loads into the loop (rounds 1-3 disease).
// h round-trips LDS each step: C-layout (col=lane&15,row=quad*4+reg) ->
// A-layout (A[m=lane&15][k=quad*8+j]). Ping-pong h buffers -> ONE barrier/step.
// PITCH=136 bf16 (=272B=17*16B): b128-aligned for every row, and rows spread
// banks (68 words == 4 mod 32) -> A-reads hit the 8-phase bandwidth floor.

#define T_STEPS 512
#define I_DIM   64
#define H_DIM   128
#define O_DIM   10
#define BT      16            // batch rows per block
#define PITCH   136           // bf16 elements per h row

typedef short  bf16x8 __attribute__((ext_vector_type(8)));
typedef float  f32x4  __attribute__((ext_vector_type(4)));

static __device__ inline short f2bf(float f) {
    union { float f; unsigned u; } v; v.f = f;
    unsigned r = v.u + 0x7FFFu + ((v.u >> 16) & 1u);   // round-to-nearest-even
    return (short)(r >> 16);
}
static __device__ inline float bf2f(short s) {
    union { unsigned u; float f; } v; v.u = ((unsigned)(unsigned short)s) << 16;
    return v.f;
}

__global__ __launch_bounds__(256)
__attribute__((amdgpu_waves_per_eu(1, 2)))
void rnn_mfma_kernel(
    const float* __restrict__ x,      // [B, T, I]
    const float* __restrict__ W_hx,   // [H, I]
    const float* __restrict__ W_hh,   // [H, H]
    const float* __restrict__ b_hh,   // [H]
    const float* __restrict__ W_ph,   // [O, H]
    const float* __restrict__ b_ph,   // [O]
    float* __restrict__ out)          // [B, O]
{
    const int b0   = blockIdx.x * BT;
    const int tid  = threadIdx.x;
    const int w    = tid >> 6;        // wave 0..3 -> N cols [32w, 32w+32)
    const int lane = tid & 63;
    const int c    = lane & 15;       // n-col within tile; batch-row for A reads
    const int q    = lane >> 4;       // quad

    __shared__ short hbuf[2][BT * PITCH];   // bf16 h, ping-pong

    // ---- Preload W_cat^T B-fragments: Bw[nt][kt], kt 0..3 = W_hh, 4..5 = W_hx.
    // B-frag: lane holds B[k=8q+j][n=c] = W_cat[n0+c][kt*32+8q+j], j=0..7
    // -> 8 consecutive fp32 of row (n0+c), cvt to bf16.
    int4 Bw[2][6];
    #pragma unroll
    for (int nt = 0; nt < 2; ++nt) {
        const int n = w * 32 + nt * 16 + c;
        #pragma unroll
        for (int kt = 0; kt < 6; ++kt) {
            const float* src = (kt < 4) ? (W_hh + n * H_DIM + kt * 32 + q * 8)
                                        : (W_hx + n * I_DIM + (kt - 4) * 32 + q * 8);
            short e[8];
            #pragma unroll
            for (int j = 0; j < 8; ++j) e[j] = f2bf(src[j]);
            Bw[nt][kt].x = ((int)(unsigned short)e[0]) | ((int)(unsigned short)e[1] << 16);
            Bw[nt][kt].y = ((int)(unsigned short)e[2]) | ((int)(unsigned short)e[3] << 16);
            Bw[nt][kt].z = ((int)(unsigned short)e[4]) | ((int)(unsigned short)e[5] << 16);
            Bw[nt][kt].w = ((int)(unsigned short)e[6]) | ((int)(unsigned short)e[7] << 16);
        }
    }
    // Pin: forbid remat/sink of the weight loads into the time loop.
    #pragma unroll
    for (int nt = 0; nt < 2; ++nt)
        #pragma unroll
        for (int kt = 0; kt < 6; ++kt)
            asm volatile("" : "+v"(Bw[nt][kt].x), "+v"(Bw[nt][kt].y),
                              "+v"(Bw[nt][kt].z), "+v"(Bw[nt][kt].w));

    const float bias0 = b_hh[w * 32 + c];
    const float bias1 = b_hh[w * 32 + 16 + c];

    // ---- h0 = 0
    for (int idx = tid; idx < BT * PITCH; idx += 256) hbuf[0][idx] = 0;

    // ---- x A-frag prefetch for t=0: lane reads x[b0+c][t][xt*32 + 8q .. +7]
    const float* xrow = x + (size_t)(b0 + c) * T_STEPS * I_DIM;
    float4 xr[4];
    {
        const float* p0 = xrow + 0 * I_DIM;
        xr[0] = *(const float4*)(p0 +      q * 8);
        xr[1] = *(const float4*)(p0 +      q * 8 + 4);
        xr[2] = *(const float4*)(p0 + 32 + q * 8);
        xr[3] = *(const float4*)(p0 + 32 + q * 8 + 4);
    }
    __syncthreads();

    for (int t = 0; t < T_STEPS; ++t) {
        const int p = t & 1;

        // Convert prefetched x -> A-frags (before xr is overwritten).
        bf16x8 Ax0, Ax1;
        Ax0[0]=f2bf(xr[0].x); Ax0[1]=f2bf(xr[0].y); Ax0[2]=f2bf(xr[0].z); Ax0[3]=f2bf(xr[0].w);
        Ax0[4]=f2bf(xr[1].x); Ax0[5]=f2bf(xr[1].y); Ax0[6]=f2bf(xr[1].z); Ax0[7]=f2bf(xr[1].w);
        Ax1[0]=f2bf(xr[2].x); Ax1[1]=f2bf(xr[2].y); Ax1[2]=f2bf(xr[2].z); Ax1[3]=f2bf(xr[2].w);
        Ax1[4]=f2bf(xr[3].x); Ax1[5]=f2bf(xr[3].y); Ax1[6]=f2bf(xr[3].z); Ax1[7]=f2bf(xr[3].w);

        // Prefetch x_{t+1}.
        {
            const int tn = (t < T_STEPS - 1) ? (t + 1) : (T_STEPS - 1);
            const float* pn = xrow + (size_t)tn * I_DIM;
            xr[0] = *(const float4*)(pn +      q * 8);
            xr[1] = *(const float4*)(pn +      q * 8 + 4);
            xr[2] = *(const float4*)(pn + 32 + q * 8);
            xr[3] = *(const float4*)(pn + 32 + q * 8 + 4);
        }

        // A-frags of h_t from LDS: A[m=c][k=kt*32+8q+j] -> ds_read_b128.
        const short* hb = hbuf[p] + c * PITCH + q * 8;
        bf16x8 Ah0 = *(const bf16x8*)(hb +  0);
        bf16x8 Ah1 = *(const bf16x8*)(hb + 32);
        bf16x8 Ah2 = *(const bf16x8*)(hb + 64);
        bf16x8 Ah3 = *(const bf16x8*)(hb + 96);

        // 12 MFMAs: x-part first (frags ready), h-part as LDS returns.
        f32x4 C0 = {0.f, 0.f, 0.f, 0.f};
        f32x4 C1 = {0.f, 0.f, 0.f, 0.f};
        C0 = __builtin_amdgcn_mfma_f32_16x16x32_bf16(Ax0, __builtin_bit_cast(bf16x8, Bw[0][4]), C0, 0, 0, 0);
        C1 = __builtin_amdgcn_mfma_f32_16x16x32_bf16(Ax0, __builtin_bit_cast(bf16x8, Bw[1][4]), C1, 0, 0, 0);
        C0 = __builtin_amdgcn_mfma_f32_16x16x32_bf16(Ax1, __builtin_bit_cast(bf16x8, Bw[0][5]), C0, 0, 0, 0);
        C1 = __builtin_amdgcn_mfma_f32_16x16x32_bf16(Ax1, __builtin_bit_cast(bf16x8, Bw[1][5]), C1, 0, 0, 0);
        C0 = __builtin_amdgcn_mfma_f32_16x16x32_bf16(Ah0, __builtin_bit_cast(bf16x8, Bw[0][0]), C0, 0, 0, 0);
        C1 = __builtin_amdgcn_mfma_f32_16x16x32_bf16(Ah0, __builtin_bit_cast(bf16x8, Bw[1][0]), C1, 0, 0, 0);
        C0 = __builtin_amdgcn_mfma_f32_16x16x32_bf16(Ah1, __builtin_bit_cast(bf16x8, Bw[0][1]), C0, 0, 0, 0);
        C1 = __builtin_amdgcn_mfma_f32_16x16x32_bf16(Ah1, __builtin_bit_cast(bf16x8, Bw[1][1]), C1, 0, 0, 0);
        C0 = __builtin_amdgcn_mfma_f32_16x16x32_bf16(Ah2, __builtin_bit_cast(bf16x8, Bw[0][2]), C0, 0, 0, 0);
        C1 = __builtin_amdgcn_mfma_f32_16x16x32_bf16(Ah2, __builtin_bit_cast(bf16x8, Bw[1][2]), C1, 0, 0, 0);
        C0 = __builtin_amdgcn_mfma_f32_16x16x32_bf16(Ah3, __builtin_bit_cast(bf16x8, Bw[0][3]), C0, 0, 0, 0);
        C1 = __builtin_amdgcn_mfma_f32_16x16x32_bf16(Ah3, __builtin_bit_cast(bf16x8, Bw[1][3]), C1, 0, 0, 0);

        // tanh + cvt + scatter into h_{t+1}. C/D: row m = 4q+r, col n.
        short* hw = hbuf[1 - p];
        #pragma unroll
        for (int r = 0; r < 4; ++r) {
            const int m = q * 4 + r;
            float s0 = C0[r] + bias0;
            float s1 = C1[r] + bias1;
            float e0 = __builtin_amdgcn_exp2f(s0 * 2.885390081777926825f);
            float e1 = __builtin_amdgcn_exp2f(s1 * 2.885390081777926825f);
            float h0 = fmaf(-2.0f, __builtin_amdgcn_rcpf(e0 + 1.0f), 1.0f);
            float h1 = fmaf(-2.0f, __builtin_amdgcn_rcpf(e1 + 1.0f), 1.0f);
            hw[m * PITCH + w * 32 + c]      = f2bf(h0);
            hw[m * PITCH + w * 32 + 16 + c] = f2bf(h1);
        }
        __syncthreads();   // one barrier per step (ping-pong makes it safe)
    }

    // ---- Epilogue: out[b0+m][o] = W_ph[o] . h_T + b_ph[o]. Final h in hbuf[0].
    if (tid < BT * O_DIM) {
        const int m = tid / O_DIM;
        const int o = tid % O_DIM;
        float acc = b_ph[o];
        #pragma unroll 4
        for (int k = 0; k < H_DIM; ++k)
            acc = fmaf(W_ph[o * H_DIM + k], bf2f(hbuf[0][m * PITCH + k]), acc);
        out[(size_t)(b0 + m) * O_DIM + o] = acc;
    }
}

extern "C" void kernel_launch(void* const* d_in, const int* in_sizes, int n_in,
                              void* d_out, int out_size, void* d_ws, size_t ws_size,
                              hipStream_t stream) {
    const float* x    = (const float*)d_in[0];
    const float* W_hx = (const float*)d_in[1];
    const float* W_hh = (const float*)d_in[2];
    const float* b_hh = (const float*)d_in[3];
    const float* W_ph = (const float*)d_in[4];
    const float* b_ph = (const float*)d_in[5];
    float* out = (float*)d_out;

    rnn_mfma_kernel<<<1024 / BT, 256, 0, stream>>>(x, W_hx, W_hh, b_hh, W_ph, b_ph, out);
}

// Round 6
// 522.612 us; speedup vs baseline: 1.4819x; 1.0619x over previous
//
#include <hip/hip_runtime.h>
#include <math.h>

// VanillaRNN via MFMA: B=1024, T=512, I=64, H=128, O=10, fp32 in/out.
// Block = 16 batch rows (64 blocks, structural cap = B/16), 256 thr = 4 waves.
// Per step: S[16x128] = V[16x192] @ W_cat^T via mfma_f32_16x16x32_bf16.
// ROUND 6 KEY FIX: __syncthreads() drains vmcnt(0) -> every step serialized a
// full x-load latency. Replaced with an LDS-only barrier (s_waitcnt lgkmcnt(0)
// + s_barrier) so depth-2 x prefetches stay in flight across steps.
// Also: accumulator chains split 6 -> 2x3 to halve serial MFMA latency.
// Weights as B-frags in VGPRs (48 regs), asm-pinned (rounds 1-3 remat disease).
// h ping-pong in LDS bf16, PITCH=136 (b128-aligned rows, banks spread -> A-frag
// ds_read_b128 at the 8-phase floor). ONE barrier per step.

#define T_STEPS 512
#define I_DIM   64
#define H_DIM   128
#define O_DIM   10
#define BT      16            // batch rows per block
#define PITCH   136           // bf16 elements per h row

typedef short  bf16x8 __attribute__((ext_vector_type(8)));
typedef float  f32x4  __attribute__((ext_vector_type(4)));

static __device__ inline short f2bf(float f) {
    union { float f; unsigned u; } v; v.f = f;
    unsigned r = v.u + 0x7FFFu + ((v.u >> 16) & 1u);   // round-to-nearest-even
    return (short)(r >> 16);
}
static __device__ inline float bf2f(short s) {
    union { unsigned u; float f; } v; v.u = ((unsigned)(unsigned short)s) << 16;
    return v.f;
}

// Barrier that does NOT drain vmcnt: h handoff only needs LDS ops complete.
// In-flight global x prefetches legally cross (write only private VGPRs).
static __device__ inline void lds_barrier() {
    asm volatile("s_waitcnt lgkmcnt(0)\n\ts_barrier" ::: "memory");
}

// One RNN step. XR holds raw fp32 x_t (loaded >=2 steps ago); after converting
// it to A-frags we reuse XR to issue the load for t+2 (stays in flight across
// the lds_barrier at the end of this step).
#define RNN_STEP(t, XR)                                                         \
    {                                                                           \
        const int p = (t) & 1;                                                  \
        /* h_t A-frags from LDS first: latency overlaps the x convert below. */ \
        const short* hb = hbuf[p] + c * PITCH + q * 8;                          \
        bf16x8 Ah0 = *(const bf16x8*)(hb +  0);                                 \
        bf16x8 Ah1 = *(const bf16x8*)(hb + 32);                                 \
        bf16x8 Ah2 = *(const bf16x8*)(hb + 64);                                 \
        bf16x8 Ah3 = *(const bf16x8*)(hb + 96);                                 \
        /* Convert x_t raw -> A-frags (vmcnt auto-wait leaves newer loads   */  \
        /* in flight), then reuse XR for the t+2 prefetch.                  */  \
        bf16x8 Ax0, Ax1;                                                        \
        Ax0[0]=f2bf(XR[0].x); Ax0[1]=f2bf(XR[0].y); Ax0[2]=f2bf(XR[0].z); Ax0[3]=f2bf(XR[0].w); \
        Ax0[4]=f2bf(XR[1].x); Ax0[5]=f2bf(XR[1].y); Ax0[6]=f2bf(XR[1].z); Ax0[7]=f2bf(XR[1].w); \
        Ax1[0]=f2bf(XR[2].x); Ax1[1]=f2bf(XR[2].y); Ax1[2]=f2bf(XR[2].z); Ax1[3]=f2bf(XR[2].w); \
        Ax1[4]=f2bf(XR[3].x); Ax1[5]=f2bf(XR[3].y); Ax1[6]=f2bf(XR[3].z); Ax1[7]=f2bf(XR[3].w); \
        {                                                                       \
            const int tn = ((t) + 2 < T_STEPS) ? (t) + 2 : T_STEPS - 1;         \
            const float* pn = xrow + (size_t)tn * I_DIM;                        \
            XR[0] = *(const float4*)(pn +      q * 8);                          \
            XR[1] = *(const float4*)(pn +      q * 8 + 4);                      \
            XR[2] = *(const float4*)(pn + 32 + q * 8);                          \
            XR[3] = *(const float4*)(pn + 32 + q * 8 + 4);                      \
        }                                                                       \
        /* 12 MFMAs in 4 independent chains of 3 (halved serial latency). */    \
        f32x4 C0a = {0.f,0.f,0.f,0.f}, C0b = {0.f,0.f,0.f,0.f};                 \
        f32x4 C1a = {0.f,0.f,0.f,0.f}, C1b = {0.f,0.f,0.f,0.f};                 \
        C0a = __builtin_amdgcn_mfma_f32_16x16x32_bf16(Ax0, __builtin_bit_cast(bf16x8, Bw[0][4]), C0a, 0, 0, 0); \
        C1a = __builtin_amdgcn_mfma_f32_16x16x32_bf16(Ax0, __builtin_bit_cast(bf16x8, Bw[1][4]), C1a, 0, 0, 0); \
        C0b = __builtin_amdgcn_mfma_f32_16x16x32_bf16(Ax1, __builtin_bit_cast(bf16x8, Bw[0][5]), C0b, 0, 0, 0); \
        C1b = __builtin_amdgcn_mfma_f32_16x16x32_bf16(Ax1, __builtin_bit_cast(bf16x8, Bw[1][5]), C1b, 0, 0, 0); \
        C0a = __builtin_amdgcn_mfma_f32_16x16x32_bf16(Ah0, __builtin_bit_cast(bf16x8, Bw[0][0]), C0a, 0, 0, 0); \
        C1a = __builtin_amdgcn_mfma_f32_16x16x32_bf16(Ah0, __builtin_bit_cast(bf16x8, Bw[1][0]), C1a, 0, 0, 0); \
        C0b = __builtin_amdgcn_mfma_f32_16x16x32_bf16(Ah1, __builtin_bit_cast(bf16x8, Bw[0][1]), C0b, 0, 0, 0); \
        C1b = __builtin_amdgcn_mfma_f32_16x16x32_bf16(Ah1, __builtin_bit_cast(bf16x8, Bw[1][1]), C1b, 0, 0, 0); \
        C0a = __builtin_amdgcn_mfma_f32_16x16x32_bf16(Ah2, __builtin_bit_cast(bf16x8, Bw[0][2]), C0a, 0, 0, 0); \
        C1a = __builtin_amdgcn_mfma_f32_16x16x32_bf16(Ah2, __builtin_bit_cast(bf16x8, Bw[1][2]), C1a, 0, 0, 0); \
        C0b = __builtin_amdgcn_mfma_f32_16x16x32_bf16(Ah3, __builtin_bit_cast(bf16x8, Bw[0][3]), C0b, 0, 0, 0); \
        C1b = __builtin_amdgcn_mfma_f32_16x16x32_bf16(Ah3, __builtin_bit_cast(bf16x8, Bw[1][3]), C1b, 0, 0, 0); \
        const f32x4 C0 = C0a + C0b;                                             \
        const f32x4 C1 = C1a + C1b;                                             \
        /* tanh + cvt + scatter into h_{t+1}. C/D: row m = 4q+r, col n. */      \
        short* hw = hbuf[1 - p];                                                \
        _Pragma("unroll")                                                       \
        for (int r = 0; r < 4; ++r) {                                           \
            const int m = q * 4 + r;                                            \
            float s0 = C0[r] + bias0;                                           \
            float s1 = C1[r] + bias1;                                           \
            float e0 = __builtin_amdgcn_exp2f(s0 * 2.885390081777926825f);      \
            float e1 = __builtin_amdgcn_exp2f(s1 * 2.885390081777926825f);      \
            float h0 = fmaf(-2.0f, __builtin_amdgcn_rcpf(e0 + 1.0f), 1.0f);     \
            float h1 = fmaf(-2.0f, __builtin_amdgcn_rcpf(e1 + 1.0f), 1.0f);     \
            hw[m * PITCH + w * 32 + c]      = f2bf(h0);                         \
            hw[m * PITCH + w * 32 + 16 + c] = f2bf(h1);                         \
        }                                                                       \
        lds_barrier();   /* LDS-only: x prefetches stay in flight */            \
    }

__global__ __launch_bounds__(256)
__attribute__((amdgpu_waves_per_eu(1, 2)))
void rnn_mfma_kernel(
    const float* __restrict__ x,      // [B, T, I]
    const float* __restrict__ W_hx,   // [H, I]
    const float* __restrict__ W_hh,   // [H, H]
    const float* __restrict__ b_hh,   // [H]
    const float* __restrict__ W_ph,   // [O, H]
    const float* __restrict__ b_ph,   // [O]
    float* __restrict__ out)          // [B, O]
{
    const int b0   = blockIdx.x * BT;
    const int tid  = threadIdx.x;
    const int w    = tid >> 6;        // wave 0..3 -> N cols [32w, 32w+32)
    const int lane = tid & 63;
    const int c    = lane & 15;       // n-col within tile; batch-row for A reads
    const int q    = lane >> 4;       // quad

    __shared__ short hbuf[2][BT * PITCH];   // bf16 h, ping-pong

    // ---- Preload W_cat^T B-fragments: Bw[nt][kt], kt 0..3 = W_hh, 4..5 = W_hx.
    int4 Bw[2][6];
    #pragma unroll
    for (int nt = 0; nt < 2; ++nt) {
        const int n = w * 32 + nt * 16 + c;
        #pragma unroll
        for (int kt = 0; kt < 6; ++kt) {
            const float* src = (kt < 4) ? (W_hh + n * H_DIM + kt * 32 + q * 8)
                                        : (W_hx + n * I_DIM + (kt - 4) * 32 + q * 8);
            short e[8];
            #pragma unroll
            for (int j = 0; j < 8; ++j) e[j] = f2bf(src[j]);
            Bw[nt][kt].x = ((int)(unsigned short)e[0]) | ((int)(unsigned short)e[1] << 16);
            Bw[nt][kt].y = ((int)(unsigned short)e[2]) | ((int)(unsigned short)e[3] << 16);
            Bw[nt][kt].z = ((int)(unsigned short)e[4]) | ((int)(unsigned short)e[5] << 16);
            Bw[nt][kt].w = ((int)(unsigned short)e[6]) | ((int)(unsigned short)e[7] << 16);
        }
    }
    // Pin: forbid remat/sink of the weight loads into the time loop.
    #pragma unroll
    for (int nt = 0; nt < 2; ++nt)
        #pragma unroll
        for (int kt = 0; kt < 6; ++kt)
            asm volatile("" : "+v"(Bw[nt][kt].x), "+v"(Bw[nt][kt].y),
                              "+v"(Bw[nt][kt].z), "+v"(Bw[nt][kt].w));

    const float bias0 = b_hh[w * 32 + c];
    const float bias1 = b_hh[w * 32 + 16 + c];

    // ---- h0 = 0
    for (int idx = tid; idx < BT * PITCH; idx += 256) hbuf[0][idx] = 0;

    // ---- Depth-2 raw-x prefetch: xrA holds t=0, xrB holds t=1.
    const float* xrow = x + (size_t)(b0 + c) * T_STEPS * I_DIM;
    float4 xrA[4], xrB[4];
    {
        const float* p0 = xrow;
        xrA[0] = *(const float4*)(p0 +      q * 8);
        xrA[1] = *(const float4*)(p0 +      q * 8 + 4);
        xrA[2] = *(const float4*)(p0 + 32 + q * 8);
        xrA[3] = *(const float4*)(p0 + 32 + q * 8 + 4);
        const float* p1 = xrow + I_DIM;
        xrB[0] = *(const float4*)(p1 +      q * 8);
        xrB[1] = *(const float4*)(p1 +      q * 8 + 4);
        xrB[2] = *(const float4*)(p1 + 32 + q * 8);
        xrB[3] = *(const float4*)(p1 + 32 + q * 8 + 4);
    }
    __syncthreads();   // once, outside the loop: full drain is fine here

    #pragma unroll 1
    for (int t = 0; t < T_STEPS; t += 2) {
        RNN_STEP(t,     xrA)
        RNN_STEP(t + 1, xrB)
    }

    // ---- Epilogue: out[b0+m][o] = W_ph[o] . h_T + b_ph[o]. Final h in hbuf[0].
    if (tid < BT * O_DIM) {
        const int m = tid / O_DIM;
        const int o = tid % O_DIM;
        float acc = b_ph[o];
        #pragma unroll 4
        for (int k = 0; k < H_DIM; ++k)
            acc = fmaf(W_ph[o * H_DIM + k], bf2f(hbuf[0][m * PITCH + k]), acc);
        out[(size_t)(b0 + m) * O_DIM + o] = acc;
    }
}

extern "C" void kernel_launch(void* const* d_in, const int* in_sizes, int n_in,
                              void* d_out, int out_size, void* d_ws, size_t ws_size,
                              hipStream_t stream) {
    const float* x    = (const float*)d_in[0];
    const float* W_hx = (const float*)d_in[1];
    const float* W_hh = (const float*)d_in[2];
    const float* b_hh = (const float*)d_in[3];
    const float* W_ph = (const float*)d_in[4];
    const float* b_ph = (const float*)d_in[5];
    float* out = (float*)d_out;

    rnn_mfma_kernel<<<1024 / BT, 256, 0, stream>>>(x, W_hx, W_hh, b_hh, W_ph, b_ph, out);
}